// Round 7
// baseline (331.629 us; speedup 1.0000x reference)
//
#include <hip/hip_runtime.h>
#include <math.h>

// DiffDispatchLP: batched (256x) PDHG, 400 iters.
// R7: TWO WAVES PER ITEM with HALO OVERLAP, one barrier/iter.
// R2-R6 established: per-item work is issue-bound on a single SIMD
// (VALUBusy = 88% of the 1-wave ceiling). 256 items use 256/1024 SIMDs.
// R3's multi-wave failure came from exchanging the WHOLE state via LDS.
// Here each wave owns half the t-range and REDUNDANTLY computes boundary
// duals from an overlapping xbar window, so only 31 dwords of xbar cross
// waves per iteration, with ONE double-buffered barrier:
//   wave0: lanes l -> t=l; owns t<=47; halo dual cell t=48; lanes 49..51
//          hold imported xbyc/xbyd@49..51 (feed shl chains); l>=52 zero.
//   wave1: lanes l -> t=l+44; lane0 holds imported xbar@44 (feeds shr);
//          halo dual cells t=45..47; owns t=48..95; l>=52 zero.
// Gather's dual reach is +1 forward (uc/msc/yeq@t+1) and -3 backward
// (ymc2@t-3), so the halo dual cells make each wave's gather fully local.
// Halo dual trajectories are bitwise mirrors (same inputs, same ops).
// Imported xbar lands in the right lanes => all DPP shifts unmodified.

#define NITER 400
#define PITER 10

__device__ __forceinline__ float dpp_shr1(float x) {  // dst[i]=src[i-1], lane0->0 (HW-verified R5)
  return __int_as_float(__builtin_amdgcn_update_dpp(
      0, __float_as_int(x), 0x138, 0xf, 0xf, true));
}
__device__ __forceinline__ float dpp_shl1(float x) {  // dst[i]=src[i+1], lane63->0 (HW-verified R5)
  return __int_as_float(__builtin_amdgcn_update_dpp(
      0, __float_as_int(x), 0x130, 0xf, 0xf, true));
}

// Full wave64 sum via DPP (VALU pipe) -- HW-verified R1.
__device__ __forceinline__ float wave_sum64(float v) {
  float r = v;
  int x;
  x = __builtin_amdgcn_update_dpp(0, __float_as_int(r), 0x111, 0xf, 0xf, true);
  r += __int_as_float(x);
  x = __builtin_amdgcn_update_dpp(0, __float_as_int(r), 0x112, 0xf, 0xf, true);
  r += __int_as_float(x);
  x = __builtin_amdgcn_update_dpp(0, __float_as_int(r), 0x114, 0xf, 0xf, true);
  r += __int_as_float(x);
  x = __builtin_amdgcn_update_dpp(0, __float_as_int(r), 0x118, 0xf, 0xf, true);
  r += __int_as_float(x);
  x = __builtin_amdgcn_update_dpp(0, __float_as_int(r), 0x142, 0xa, 0xf, true);
  r += __int_as_float(x);
  x = __builtin_amdgcn_update_dpp(0, __float_as_int(r), 0x143, 0xc, 0xf, true);
  r += __int_as_float(x);
  return __int_as_float(__builtin_amdgcn_readlane(__float_as_int(r), 63));
}

__global__ __launch_bounds__(128, 1)
void lp_solve_kernel(const float* __restrict__ price, float* __restrict__ out) {
  // exchange slots, double-buffered (35 per buffer):
  //  B+0..3  xbc@44..47   B+4..7  xbd@44..47   B+8..11 xbs@44..47
  //  B+12..15 xbyc@44..47 B+16..19 xbyd@44..47            (w0 -> w1)
  //  B+20..23 xbyc@48..51 B+24..27 xbyd@48..51
  //  B+28 xbc@48  B+29 xbd@48  B+30 xbs@48                (w1 -> w0)
  //  B+31,32 TC partials; 33,34 power-norm partials (buffer0 only)
  __shared__ float ex[70];

  const int tid = threadIdx.x, lane = tid & 63, wid = tid >> 6, bi = blockIdx.x;
  const double ETA_D = sqrt(0.91);
  const float cET = (float)(-(ETA_D * 0.25));  // eq coeff on c
  const float cDE = (float)(0.25 / ETA_D);     // eq coeff on d

  const int t = wid ? (lane + 44) : lane;
  const bool ownB = wid ? (lane >= 4 && lane <= 51) : (lane <= 47);
  const float own = ownB ? 1.f : 0.f;
  // dual-update masks (row existence AND halo-domain bounds)
  const float dact = (wid ? (lane >= 1 && lane <= 51) : (lane <= 48)) ? 1.f : 0.f;
  const float m_r  = (wid ? (lane >= 1 && lane <= 51) : (lane >= 1 && lane <= 48)) ? 1.f : 0.f;
  const float m_sw = (wid ? (lane >= 1 && lane <= 50) : (lane <= 48)) ? 1.f : 0.f;
  const float m_m1 = (wid ? (lane >= 1 && lane <= 50) : (lane <= 48)) ? 1.f : 0.f;
  const float m_m2 = (wid ? (lane >= 1 && lane <= 49) : (lane <= 48)) ? 1.f : 0.f;
  const float m_m3 = (wid ? (lane >= 1 && lane <= 48) : (lane <= 48)) ? 1.f : 0.f;
  const bool isL95 = (wid == 1 && lane == 51);   // t = 95

  // ---------------- state (registers; halo cells mirror the owner) --------
  float xc = 0, xd = 0, xyc = 0, xyd = 0, xs = 0;
  float xbc = 0, xbd = 0, xbyc = 0, xbyd = 0, xbs = 0;
  float qc = 0, qd = 0;
  float yb0=0,yb1=0,yb2=0,yb3=0,yb4=0,yb5=0,yb6=0,yb7=0,yb8=0,yb9=0,yb10=0,yb11=0,yb12=0;
  float ymc0=0, ymc1=0, ymc2=0, ymd0=0, ymd1=0, ymd2=0;
  float yr0=0, yr1=0, yr2=0, yr3=0, sw0=0, sw1=0, yeq=0;
  float uc=0, ud=0, msc=0, msd=0;
  float ytc = 0.f, yeq96 = 0.f;
  float sigv = 0.f, tauv = 0.f;
  float sa=0, sr=0, ssw=0, sm1=0, sm2=0, sm3=0, ta=0;

  // ---------------- phase B: row dots / dual updates ----------------
  auto phaseB = [&](bool power) {
    float pxc = dpp_shr1(xbc), pxd = dpp_shr1(xbd), pxs = dpp_shr1(xbs);
    float pxyc = dpp_shr1(xbyc), pxyd = dpp_shr1(xbyd);
    float nyc1 = dpp_shl1(xbyc), nyc2 = dpp_shl1(nyc1), nyc3 = dpp_shl1(nyc2);
    float nyd1 = dpp_shl1(xbyd), nyd2 = dpp_shl1(nyd1), nyd3 = dpp_shl1(nyd2);
    float bc = xbyc - pxyc, bd = xbyd - pxyd;
    float dc = xbc - pxc, dd = xbd - pxd;
    if (power) {
      yb0 = xbc;   yb1 = xbd;
      yb2 = -xbc;  yb3 = -xbd;
      yb4 = -xbyc; yb5 = xbyc;
      yb6 = -xbyd; yb7 = xbyd;
      yb8 = -xbs;  yb9 = xbs;
      yb10 = xbyc + xbyd;
      yb11 = xbc - 195.f * xbyc;
      yb12 = xbd - 195.f * xbyd;
      ymc0 = m_m1 * (bc - nyc1); ymc1 = m_m2 * (bc - nyc2); ymc2 = m_m3 * (bc - nyc3);
      ymd0 = m_m1 * (bd - nyd1); ymd1 = m_m2 * (bd - nyd2); ymd2 = m_m3 * (bd - nyd3);
      yr0 = m_r * dc; yr1 = -m_r * dc; yr2 = m_r * dd; yr3 = -m_r * dd;
      sw0 = m_sw * (xbyc + nyd1); sw1 = m_sw * (xbyd + nyc1);
      yeq = dact * (xbs - pxs + cET * xbc + cDE * xbd);
      yeq96 = __int_as_float(__builtin_amdgcn_readlane(__float_as_int(xbs), 51));
    } else {
      yb0  = fmaxf(yb0  + sa * (xbc - 195.f), 0.f);
      yb1  = fmaxf(yb1  + sa * (xbd - 195.f), 0.f);
      yb2  = fmaxf(yb2  - sa * xbc,           0.f);
      yb3  = fmaxf(yb3  - sa * xbd,           0.f);
      yb4  = fmaxf(yb4  - sa * xbyc,          0.f);
      yb5  = fmaxf(yb5  + sa * (xbyc - 1.f),  0.f);
      yb6  = fmaxf(yb6  - sa * xbyd,          0.f);
      yb7  = fmaxf(yb7  + sa * (xbyd - 1.f),  0.f);
      yb8  = fmaxf(yb8  - sa * xbs,           0.f);
      yb9  = fmaxf(yb9  + sa * (xbs - 800.f), 0.f);
      yb10 = fmaxf(yb10 + sa * (xbyc + xbyd - 1.f), 0.f);
      yb11 = fmaxf(yb11 + sa * (xbc - 195.f * xbyc), 0.f);
      yb12 = fmaxf(yb12 + sa * (xbd - 195.f * xbyd), 0.f);
      ymc0 = fmaxf(ymc0 + sm1 * (bc - nyc1), 0.f);
      ymc1 = fmaxf(ymc1 + sm2 * (bc - nyc2), 0.f);
      ymc2 = fmaxf(ymc2 + sm3 * (bc - nyc3), 0.f);
      ymd0 = fmaxf(ymd0 + sm1 * (bd - nyd1), 0.f);
      ymd1 = fmaxf(ymd1 + sm2 * (bd - nyd2), 0.f);
      ymd2 = fmaxf(ymd2 + sm3 * (bd - nyd3), 0.f);
      yr0 = fmaxf(yr0 + sr * (dc - 65.f),  0.f);
      yr1 = fmaxf(yr1 + sr * (-dc - 65.f), 0.f);
      yr2 = fmaxf(yr2 + sr * (dd - 65.f),  0.f);
      yr3 = fmaxf(yr3 + sr * (-dd - 65.f), 0.f);
      sw0 = fmaxf(sw0 + ssw * (xbyc + nyd1 - 1.f), 0.f);
      sw1 = fmaxf(sw1 + ssw * (xbyd + nyc1 - 1.f), 0.f);
      yeq += sa * (xbs - pxs + cET * xbc + cDE * xbd);
      float s95 = __int_as_float(__builtin_amdgcn_readlane(__float_as_int(xbs), 51));
      yeq96 += sigv * s95;   // only wave1's copy is consumed (isL95)
    }
    uc = yr0 - yr1; ud = yr2 - yr3;
    msc = ymc0 + ymc1 + ymc2; msd = ymd0 + ymd1 + ymd2;
  };

  // ---------------- phase A: K^T y gather ----------------
  float gc, gd, gyc, gyd, gs;
  auto gather = [&]() {
    float ucn = dpp_shl1(uc), udn = dpp_shl1(ud);
    float mscn = dpp_shl1(msc), msdn = dpp_shl1(msd);
    float eqn = dpp_shl1(yeq);
    eqn = isL95 ? -yeq96 : eqn;
    float sw1p = dpp_shr1(sw1), sw0p = dpp_shr1(sw0);
    float pc1 = dpp_shr1(ymc0);
    float a1 = dpp_shr1(ymc1); float pc2 = dpp_shr1(a1);
    float a2 = dpp_shr1(ymc2); float a3 = dpp_shr1(a2); float pc3 = dpp_shr1(a3);
    float b1 = dpp_shr1(ymd0); float pd1 = b1;
    float b2 = dpp_shr1(ymd1); float pd2 = dpp_shr1(b2);
    float b3 = dpp_shr1(ymd2); float b4 = dpp_shr1(b3); float pd3 = dpp_shr1(b4);
    gc = (yb0 - yb2 + yb11) + uc - ucn + 0.25f * ytc + cET * yeq;
    gd = (yb1 - yb3 + yb12) + ud - udn + cDE * yeq;
    gyc = (yb5 - yb4 + yb10 - 195.f * yb11)
        + sw0 + sw1p + msc - mscn - pc1 - pc2 - pc3;
    gyd = (yb7 - yb6 + yb10 - 195.f * yb12)
        + sw1 + sw0p + msd - msdn - pd1 - pd2 - pd3;
    gs = (yb9 - yb8) + yeq - eqn;
  };

  // ---------------- xbar halo exchange + TC partial combine --------------
  // ONE barrier; double-buffered by B so iter n+1 writes can't overtake
  // iter n reads (both are separated by barrier n+1's arrival).
  auto exchange = [&](int B, float part) -> float {
    if (wid == 0) {
      if (lane >= 44 && lane < 48) {
        int i = lane - 44;
        ex[B + i] = xbc; ex[B + 4 + i] = xbd; ex[B + 8 + i] = xbs;
        ex[B + 12 + i] = xbyc; ex[B + 16 + i] = xbyd;
      }
    } else {
      if (lane >= 4 && lane < 8) {
        int i = lane - 4;
        ex[B + 20 + i] = xbyc; ex[B + 24 + i] = xbyd;
      }
      if (lane == 4) { ex[B + 28] = xbc; ex[B + 29] = xbd; ex[B + 30] = xbs; }
    }
    if (lane == 0) ex[B + 31 + wid] = part;
    __syncthreads();
    if (wid == 0) {
      if (lane >= 48 && lane < 52) {
        int i = lane - 48;
        xbyc = ex[B + 20 + i]; xbyd = ex[B + 24 + i];
      }
      if (lane == 48) { xbc = ex[B + 28]; xbd = ex[B + 29]; xbs = ex[B + 30]; }
    } else {
      if (lane < 4) {
        xbc = ex[B + lane]; xbd = ex[B + 4 + lane]; xbs = ex[B + 8 + lane];
        xbyc = ex[B + 12 + lane]; xbyd = ex[B + 16 + lane];
      }
    }
    return ex[B + 31] + ex[B + 32];
  };

  // ================= power iteration: ||K||_2 =================
  {
    float vinit = (lane <= 51) ? 1.f : 0.f;  // all valid t on this wave
    xbc = vinit; xbd = vinit; xbyc = vinit; xbyd = vinit; xbs = vinit;
  }
  ytc = 0.25f * 96.f;  // TC raw dot of the all-ones start vector
  float lam2 = 1.f;
  for (int pit = 0; pit < PITER; ++pit) {
    phaseB(true);
    gather();
    float part = wave_sum64(own * (gc * gc + gd * gd + gyc * gyc + gyd * gyd + gs * gs));
    if (lane == 0) ex[33 + wid] = part;
    __syncthreads();
    lam2 = sqrtf(ex[33] + ex[34]);
    float inv = own / lam2;
    xbc = gc * inv; xbd = gd * inv; xbyc = gyc * inv; xbyd = gyd * inv; xbs = gs * inv;
    float pc = wave_sum64(own * xbc);
    float tot = exchange(0, pc);   // refill halo xbar; combine TC partials
    ytc = 0.25f * tot;             // raw TC dot for next pit's gather
  }
  tauv = (float)(0.9 / sqrt((double)lam2));
  sigv = tauv;
  sa = sigv * dact; sr = sigv * m_r; ssw = sigv * m_sw;
  sm1 = sigv * m_m1; sm2 = sigv * m_m2; sm3 = sigv * m_m3;
  ta = tauv * own;

  // reset all state for PDHG
  yb0=yb1=yb2=yb3=yb4=yb5=yb6=yb7=yb8=yb9=yb10=yb11=yb12=0.f;
  ymc0=ymc1=ymc2=ymd0=ymd1=ymd2=0.f;
  yr0=yr1=yr2=yr3=sw0=sw1=yeq=0.f;
  uc=ud=msc=msd=0.f;
  xbc=xbd=xbyc=xbyd=xbs=0.f;
  xc=xd=xyc=xyd=xs=0.f;
  ytc = 0.f; yeq96 = 0.f;

  {  // q loads (non-own lanes nullified by ta)
    int ti = (t <= 95) ? t : 95;
    float pr = price[bi * 96 + ti];
    qc = 0.25f * pr; qd = -0.25f * pr;
  }

  // ================= PDHG =================
#pragma unroll 1
  for (int it = 0; it < NITER; ++it) {
    gather();
    float xa;
    xa = xc - ta * (qc + gc);  xbc = 2.f * xa - xc;  xc = xa;
    xa = xd - ta * (qd + gd);  xbd = 2.f * xa - xd;  xd = xa;
    xa = xyc - ta * gyc;       xbyc = 2.f * xa - xyc; xyc = xa;
    xa = xyd - ta * gyd;       xbyd = 2.f * xa - xyd; xyd = xa;
    xa = xs - ta * gs;         xbs = 2.f * xa - xs;  xs = xa;
    float pc = wave_sum64(own * xbc);
    float tot = exchange((it & 1) * 35, pc);
    ytc = fmaxf(ytc + sigv * (0.25f * tot - 1200.f), 0.f);
    phaseB(false);
  }

  // output: c then d, each (256,96)
  if (ownB) {
    out[bi * 96 + t] = xc;
    out[24576 + bi * 96 + t] = xd;
  }
}

extern "C" void kernel_launch(void* const* d_in, const int* in_sizes, int n_in,
                              void* d_out, int out_size, void* d_ws, size_t ws_size,
                              hipStream_t stream) {
  const float* price = (const float*)d_in[0];
  float* outp = (float*)d_out;
  hipLaunchKernelGGL(lp_solve_kernel, dim3(256), dim3(128), 0, stream, price, outp);
}

// Round 8
// 302.992 us; speedup vs baseline: 1.0945x; 1.0945x over previous
//
#include <hip/hip_runtime.h>
#include <math.h>

// DiffDispatchLP: batched (256x) PDHG, 400 iters.
// R8: BLOCK LAYOUT (lane l holds t=l in .x, t=l+48 in .y) + full v2 packing.
// R1-R7 established: (1) any per-iter __syncthreads exchange costs ~1000cy at
// 1 block/CU -> single-wave-per-item is optimal; (2) R6 is issue-bound at
// ~473 inst/iter, but ideal f32-packing needs only ~300; (3) R6's interleaved
// (2l,2l+1) layout mixes .x/.y across every shift, forcing pair-reassembly
// movs that block v_pk_*_f32 formation. Block layout makes every t+-k shift
// component-preserving (2 DPPs, no movs; 1 boundary lane fixed via
// readlane+cndmask), so all dual/gather arithmetic stays on natural v2 pairs.
// Arithmetic expression trees identical to R6 (tolerance-safe).
//
// LP recap (T=96): vars c,d,yc,yd,s per t. Rows: box(13/t), ramp(4/t,t>=1),
// switch(2/t,t<=94), min-dur(v,k=1..3,t<=95-k), total-charge
// (0.25*sum(c)<=1200), eq(t=0..95: s[t]-s[t-1]+cET*c+cDE*d=0), eq96 (s[95]=0).

#define NITER 400
#define PITER 10

typedef float v2 __attribute__((ext_vector_type(2)));

__device__ __forceinline__ float dpp_shr1(float x) {  // dst[i]=src[i-1], lane0->0 (HW-verified R5)
  return __int_as_float(__builtin_amdgcn_update_dpp(
      0, __float_as_int(x), 0x138, 0xf, 0xf, true));
}
__device__ __forceinline__ float dpp_shl1(float x) {  // dst[i]=src[i+1], lane63->0 (HW-verified R5)
  return __int_as_float(__builtin_amdgcn_update_dpp(
      0, __float_as_int(x), 0x130, 0xf, 0xf, true));
}
__device__ __forceinline__ float rl(float x, int l) {  // readlane (uniform l)
  return __int_as_float(__builtin_amdgcn_readlane(__float_as_int(x), l));
}

// Full wave64 sum via DPP (VALU pipe) -- HW-verified R1.
__device__ __forceinline__ float wave_sum64(float v) {
  float r = v;
  int x;
  x = __builtin_amdgcn_update_dpp(0, __float_as_int(r), 0x111, 0xf, 0xf, true);
  r += __int_as_float(x);
  x = __builtin_amdgcn_update_dpp(0, __float_as_int(r), 0x112, 0xf, 0xf, true);
  r += __int_as_float(x);
  x = __builtin_amdgcn_update_dpp(0, __float_as_int(r), 0x114, 0xf, 0xf, true);
  r += __int_as_float(x);
  x = __builtin_amdgcn_update_dpp(0, __float_as_int(r), 0x118, 0xf, 0xf, true);
  r += __int_as_float(x);
  x = __builtin_amdgcn_update_dpp(0, __float_as_int(r), 0x142, 0xa, 0xf, true);
  r += __int_as_float(x);
  x = __builtin_amdgcn_update_dpp(0, __float_as_int(r), 0x143, 0xc, 0xf, true);
  r += __int_as_float(x);
  return __int_as_float(__builtin_amdgcn_readlane(__float_as_int(r), 63));
}

__global__ __launch_bounds__(64, 1)
void lp_solve_kernel(const float* __restrict__ price, float* __restrict__ out) {
  const int lane = threadIdx.x;
  const int bi = blockIdx.x;
  const double ETA_D = sqrt(0.91);
  const float cET = (float)(-(ETA_D * 0.25));  // eq coeff on c
  const float cDE = (float)(0.25 / ETA_D);     // eq coeff on d
  const v2 Z = {0.f, 0.f};

  const bool actB = (lane < 48);
  const float av = actB ? 1.f : 0.f;           // both halves valid iff lane<48
  const bool L0 = (lane == 0), L47 = (lane == 47);

  // row-existence masks per half (.x: t=lane, .y: t=lane+48)
  const v2 m_r  = { (lane >= 1 && lane < 48) ? 1.f : 0.f, av };  // ramp t>=1
  const v2 m_sw = { av, (lane <= 46) ? 1.f : 0.f };              // sw t<=94
  const v2 m_m1 = { av, (lane <= 46) ? 1.f : 0.f };              // md k=1 t<=94
  const v2 m_m2 = { av, (lane <= 45) ? 1.f : 0.f };              // md k=2 t<=93
  const v2 m_m3 = { av, (lane <= 44) ? 1.f : 0.f };              // md k=3 t<=92

  // ---------------- state (all registers, block-packed) ----------------
  v2 xc = Z, xd = Z, xyc = Z, xyd = Z, xs = Z;
  v2 xbc = Z, xbd = Z, xbyc = Z, xbyd = Z, xbs = Z;
  v2 qc = Z, qd = Z;
  v2 yb[13];
#pragma unroll
  for (int i = 0; i < 13; ++i) yb[i] = Z;
  v2 ymc0 = Z, ymc1 = Z, ymc2 = Z, ymd0 = Z, ymd1 = Z, ymd2 = Z;
  v2 yr0 = Z, yr1 = Z, yr2 = Z, yr3 = Z, sw0 = Z, sw1 = Z, yeq = Z;
  v2 uc = Z, ud = Z, msc = Z, msd = Z;
  float yeq96 = 0.f, ytc = 0.f;
  float sigv = 0.f, tauv = 0.f, sa = 0.f;
  v2 sr = Z, ssw = Z, sm1 = Z, sm2 = Z, sm3 = Z;

  // component-preserving lane shifts with single-boundary fix
  auto prev1 = [&](v2 X) -> v2 {   // slot t <- X[t-1]; t=0 -> 0
    float h = rl(X.x, 47);         // t=47 value feeds .y slot t=48
    v2 r;
    r.x = dpp_shr1(X.x);
    float ry = dpp_shr1(X.y);
    r.y = L0 ? h : ry;
    return r;
  };
  auto next1 = [&](v2 X) -> v2 {   // slot t <- X[t+1]; t=95 -> 0
    float h = rl(X.y, 0);          // t=48 value feeds .x slot t=47
    v2 r;
    r.y = dpp_shl1(X.y);           // lane47 <- lane48 = 0 (t=96 absent)
    float rx = dpp_shl1(X.x);
    r.x = L47 ? h : rx;
    return r;
  };

  // ---------------- phase B: row dots / dual updates ----------------
  auto phaseB = [&](bool power) {
    v2 pxc = prev1(xbc), pxd = prev1(xbd), pxs = prev1(xbs);
    v2 pxyc = prev1(xbyc), pxyd = prev1(xbyd);
    v2 nyc1 = next1(xbyc), nyc2 = next1(nyc1), nyc3 = next1(nyc2);
    v2 nyd1 = next1(xbyd), nyd2 = next1(nyd1), nyd3 = next1(nyd2);
    v2 bc = xbyc - pxyc, bd = xbyd - pxyd;
    v2 dc = xbc - pxc, dd = xbd - pxd;
    if (power) {
      yb[0] = xbc;   yb[1] = xbd;
      yb[2] = -xbc;  yb[3] = -xbd;
      yb[4] = -xbyc; yb[5] = xbyc;
      yb[6] = -xbyd; yb[7] = xbyd;
      yb[8] = -xbs;  yb[9] = xbs;
      yb[10] = xbyc + xbyd;
      yb[11] = xbc - 195.f * xbyc;
      yb[12] = xbd - 195.f * xbyd;
      ymc0 = m_m1 * (bc - nyc1); ymc1 = m_m2 * (bc - nyc2); ymc2 = m_m3 * (bc - nyc3);
      ymd0 = m_m1 * (bd - nyd1); ymd1 = m_m2 * (bd - nyd2); ymd2 = m_m3 * (bd - nyd3);
      yr0 = m_r * dc; yr1 = -yr0; yr2 = m_r * dd; yr3 = -yr2;
      sw0 = m_sw * (xbyc + nyd1); sw1 = m_sw * (xbyd + nyc1);
      yeq = av * (xbs - pxs + cET * xbc + cDE * xbd);
      yeq96 = rl(xbs.y, 47);
    } else {
      yb[0]  = __builtin_elementwise_max(yb[0]  + sa * (xbc - 195.f), Z);
      yb[1]  = __builtin_elementwise_max(yb[1]  + sa * (xbd - 195.f), Z);
      yb[2]  = __builtin_elementwise_max(yb[2]  - sa * xbc,           Z);
      yb[3]  = __builtin_elementwise_max(yb[3]  - sa * xbd,           Z);
      yb[4]  = __builtin_elementwise_max(yb[4]  - sa * xbyc,          Z);
      yb[5]  = __builtin_elementwise_max(yb[5]  + sa * (xbyc - 1.f),  Z);
      yb[6]  = __builtin_elementwise_max(yb[6]  - sa * xbyd,          Z);
      yb[7]  = __builtin_elementwise_max(yb[7]  + sa * (xbyd - 1.f),  Z);
      yb[8]  = __builtin_elementwise_max(yb[8]  - sa * xbs,           Z);
      yb[9]  = __builtin_elementwise_max(yb[9]  + sa * (xbs - 800.f), Z);
      yb[10] = __builtin_elementwise_max(yb[10] + sa * (xbyc + xbyd - 1.f), Z);
      yb[11] = __builtin_elementwise_max(yb[11] + sa * (xbc - 195.f * xbyc), Z);
      yb[12] = __builtin_elementwise_max(yb[12] + sa * (xbd - 195.f * xbyd), Z);
      ymc0 = __builtin_elementwise_max(ymc0 + sm1 * (bc - nyc1), Z);
      ymc1 = __builtin_elementwise_max(ymc1 + sm2 * (bc - nyc2), Z);
      ymc2 = __builtin_elementwise_max(ymc2 + sm3 * (bc - nyc3), Z);
      ymd0 = __builtin_elementwise_max(ymd0 + sm1 * (bd - nyd1), Z);
      ymd1 = __builtin_elementwise_max(ymd1 + sm2 * (bd - nyd2), Z);
      ymd2 = __builtin_elementwise_max(ymd2 + sm3 * (bd - nyd3), Z);
      yr0 = __builtin_elementwise_max(yr0 + sr * (dc - 65.f),  Z);
      yr1 = __builtin_elementwise_max(yr1 + sr * (-dc - 65.f), Z);
      yr2 = __builtin_elementwise_max(yr2 + sr * (dd - 65.f),  Z);
      yr3 = __builtin_elementwise_max(yr3 + sr * (-dd - 65.f), Z);
      sw0 = __builtin_elementwise_max(sw0 + ssw * (xbyc + nyd1 - 1.f), Z);
      sw1 = __builtin_elementwise_max(sw1 + ssw * (xbyd + nyc1 - 1.f), Z);
      yeq += sa * (xbs - pxs + cET * xbc + cDE * xbd);
      yeq96 += sigv * rl(xbs.y, 47);
    }
    uc = yr0 - yr1; ud = yr2 - yr3;
    msc = ymc0 + ymc1 + ymc2; msd = ymd0 + ymd1 + ymd2;
    // total-charge (wave-uniform)
    float tot = wave_sum64(xbc.x + xbc.y);
    if (power) ytc = 0.25f * tot;
    else ytc = fmaxf(ytc + sigv * (0.25f * tot - 1200.f), 0.f);
  };

  // ---------------- phase A: K^T y gather ----------------
  v2 gc, gd, gyc, gyd, gs;
  auto gather = [&]() {
    v2 ucn = next1(uc), udn = next1(ud);
    v2 mscn = next1(msc), msdn = next1(msd);
    v2 eqn = next1(yeq);
    eqn.y = L47 ? -yeq96 : eqn.y;              // slot t=95: next row is eq96
    v2 sw1p = prev1(sw1), sw0p = prev1(sw0);
    v2 pc1 = prev1(ymc0);
    v2 t1 = prev1(ymc1); v2 pc2 = prev1(t1);
    v2 t2 = prev1(ymc2); v2 t3 = prev1(t2); v2 pc3 = prev1(t3);
    v2 pd1 = prev1(ymd0);
    v2 u1 = prev1(ymd1); v2 pd2 = prev1(u1);
    v2 u2 = prev1(ymd2); v2 u3 = prev1(u2); v2 pd3 = prev1(u3);
    gc = (yb[0] - yb[2] + yb[11]) + uc - ucn + 0.25f * ytc + cET * yeq;
    gd = (yb[1] - yb[3] + yb[12]) + ud - udn + cDE * yeq;
    gyc = (yb[5] - yb[4] + yb[10] - 195.f * yb[11])
        + sw0 + sw1p + msc - mscn - pc1 - pc2 - pc3;
    gyd = (yb[7] - yb[6] + yb[10] - 195.f * yb[12])
        + sw1 + sw0p + msd - msdn - pd1 - pd2 - pd3;
    gs = (yb[9] - yb[8]) + yeq - eqn;
  };

  // ================= power iteration: ||K||_2 =================
  xbc = av; xbd = av; xbyc = av; xbyd = av; xbs = av;
  float lam2 = 1.f;
  for (int pit = 0; pit < PITER; ++pit) {
    phaseB(true);
    gather();
    v2 pv = gc * gc + gd * gd + gyc * gyc + gyd * gyd + gs * gs;
    float part = (pv.x + pv.y) * av;
    lam2 = sqrtf(wave_sum64(part));
    float inv = av / lam2;
    xbc = gc * inv; xbd = gd * inv;
    xbyc = gyc * inv; xbyd = gyd * inv; xbs = gs * inv;
  }
  tauv = (float)(0.9 / sqrt((double)lam2));
  sigv = tauv;
  // sigma*mask row multipliers (loop-invariant)
  sa = sigv * av;
  sr = sigv * m_r; ssw = sigv * m_sw;
  sm1 = sigv * m_m1; sm2 = sigv * m_m2; sm3 = sigv * m_m3;

  // reset all state for PDHG
#pragma unroll
  for (int i = 0; i < 13; ++i) yb[i] = Z;
  ymc0 = Z; ymc1 = Z; ymc2 = Z; ymd0 = Z; ymd1 = Z; ymd2 = Z;
  yr0 = Z; yr1 = Z; yr2 = Z; yr3 = Z; sw0 = Z; sw1 = Z; yeq = Z;
  uc = Z; ud = Z; msc = Z; msd = Z;
  xbc = Z; xbd = Z; xbyc = Z; xbyd = Z; xbs = Z;
  xc = Z; xd = Z; xyc = Z; xyd = Z; xs = Z;
  yeq96 = 0.f; ytc = 0.f;

  // q loads (lanes >=48 nullified by ta)
  {
    const int ti = actB ? lane : 0;
    float p0 = price[bi * 96 + ti];
    float p1 = price[bi * 96 + 48 + ti];
    qc = (v2){ 0.25f * p0, 0.25f * p1 };
    qd = (v2){ -0.25f * p0, -0.25f * p1 };
  }

  // ================= PDHG =================
  const float ta = tauv * av;
#pragma unroll 1
  for (int it = 0; it < NITER; ++it) {
    gather();
    {
      v2 xa;
      xa = xc  - ta * (qc + gc);  xbc  = 2.f * xa - xc;  xc  = xa;
      xa = xd  - ta * (qd + gd);  xbd  = 2.f * xa - xd;  xd  = xa;
      xa = xyc - ta * gyc;        xbyc = 2.f * xa - xyc; xyc = xa;
      xa = xyd - ta * gyd;        xbyd = 2.f * xa - xyd; xyd = xa;
      xa = xs  - ta * gs;         xbs  = 2.f * xa - xs;  xs  = xa;
    }
    phaseB(false);
  }

  // output: c then d, each (256,96)
  if (actB) {
    out[bi * 96 + lane]              = xc.x;
    out[bi * 96 + 48 + lane]         = xc.y;
    out[24576 + bi * 96 + lane]      = xd.x;
    out[24576 + bi * 96 + 48 + lane] = xd.y;
  }
}

extern "C" void kernel_launch(void* const* d_in, const int* in_sizes, int n_in,
                              void* d_out, int out_size, void* d_ws, size_t ws_size,
                              hipStream_t stream) {
  const float* price = (const float*)d_in[0];
  float* outp = (float*)d_out;
  hipLaunchKernelGGL(lp_solve_kernel, dim3(256), dim3(64), 0, stream, price, outp);
}

// Round 9
// 217.219 us; speedup vs baseline: 1.5267x; 1.3949x over previous
//
#include <hip/hip_runtime.h>
#include <math.h>

// DiffDispatchLP: batched (256x) PDHG, 400 iters.
// R9: R6 (best, 180us) + two zero-risk scheduling changes.
// Established by R1-R8: per-item time = ONE wave's serial issue stream
// (cross-wave sync ~1000cy/iter: R3/R7; LDS state ~650cy: R2; block layout
// shift fixups +100 ops: R8; interleaved (2l,2l+1) layout is shift-optimal:
// t+-1 = 1 DPP, other component is a free register rename). R6 measured
// ~88% issue rate -> ~133cy/iter of intra-wave stalls, consistent with
// gfx9 DPP read-after-VALU-write hazards (2 wait states) inside the tight
// shift chains and wave_sum64. R9:
//  (1) #pragma unroll 2 on the PDHG loop: second instruction stream for the
//      scheduler to fill DPP hazard slots; x=xa copies elided by renaming.
//  (2) TC wave_sum64 + yeq96 readlane hoisted to the TOP of phaseB so their
//      serial chains overlap the whole dual-update block (they depend only
//      on xbar, which phaseB never writes).
// Numerics identical to R6.
//
// Lane layout: lane l holds t=2l (.x) and t=2l+1 (.y), l<48. All K/K^T
// couplings are t-offsets +-1..3 => same-lane or 1-2 lane DPP shifts.
// Row-existence masks folded into per-row sigma multipliers; lanes >=48 and
// nonexistent rows carry exact zeros so shift edges read natural zeros.

#define NITER 400
#define PITER 10

typedef float v2 __attribute__((ext_vector_type(2)));

// ---- DPP lane shifts (wave modes; HW-verified R1/R5). ----
__device__ __forceinline__ float dpp_shr1(float x) {  // dst[i] = src[i-1], lane0 -> 0
  return __int_as_float(__builtin_amdgcn_update_dpp(
      0, __float_as_int(x), 0x138, 0xf, 0xf, true));   // wave_shr:1
}
__device__ __forceinline__ float dpp_shl1(float x) {  // dst[i] = src[i+1], lane63 -> 0
  return __int_as_float(__builtin_amdgcn_update_dpp(
      0, __float_as_int(x), 0x130, 0xf, 0xf, true));   // wave_shl:1
}

// Full wave64 sum via DPP (VALU pipe) -- HW-verified R1.
__device__ __forceinline__ float wave_sum64(float v) {
  float r = v;
  int x;
  x = __builtin_amdgcn_update_dpp(0, __float_as_int(r), 0x111, 0xf, 0xf, true);
  r += __int_as_float(x);
  x = __builtin_amdgcn_update_dpp(0, __float_as_int(r), 0x112, 0xf, 0xf, true);
  r += __int_as_float(x);
  x = __builtin_amdgcn_update_dpp(0, __float_as_int(r), 0x114, 0xf, 0xf, true);
  r += __int_as_float(x);
  x = __builtin_amdgcn_update_dpp(0, __float_as_int(r), 0x118, 0xf, 0xf, true);
  r += __int_as_float(x);
  x = __builtin_amdgcn_update_dpp(0, __float_as_int(r), 0x142, 0xa, 0xf, true);
  r += __int_as_float(x);
  x = __builtin_amdgcn_update_dpp(0, __float_as_int(r), 0x143, 0xc, 0xf, true);
  r += __int_as_float(x);
  return __int_as_float(__builtin_amdgcn_readlane(__float_as_int(r), 63));
}

__global__ __launch_bounds__(64, 1)
void lp_solve_kernel(const float* __restrict__ price, float* __restrict__ out) {
  const int lane = threadIdx.x;
  const int bi = blockIdx.x;
  const double ETA_D = sqrt(0.91);
  const float cET = (float)(-(ETA_D * 0.25));  // -ETA*DT (eq coeff on c)
  const float cDE = (float)(0.25 / ETA_D);     // DT/ETA (eq coeff on d)
  const v2 Z = {0.f, 0.f};

  const float act = (lane < 48) ? 1.f : 0.f;
  // row-existence masks packed over p (power mode); PDHG uses sigma*mask.
  const v2 m_r  = { (lane >= 1 && lane < 48) ? 1.f : 0.f, act };   // ramp t>=1
  const v2 m_sw = { act, (lane <= 46) ? 1.f : 0.f };               // sw t<=94
  const v2 m_md[3] = {
    { act,                      (lane <= 46) ? 1.f : 0.f },        // k=1: t<=94
    { (lane <= 46) ? 1.f : 0.f, (lane <= 46) ? 1.f : 0.f },        // k=2: t<=93
    { (lane <= 46) ? 1.f : 0.f, (lane <= 45) ? 1.f : 0.f }         // k=3: t<=92
  };

  // ---------------- state (all registers, p-packed) ----------------
  v2 xc = Z, xd = Z, xyc = Z, xyd = Z, xs = Z;
  v2 xbc = Z, xbd = Z, xbyc = Z, xbyd = Z, xbs = Z;
  v2 qc = Z, qd = Z;
  v2 yb[13];
#pragma unroll
  for (int i = 0; i < 13; ++i) yb[i] = Z;
  v2 ymc[3] = {Z, Z, Z}, ymd[3] = {Z, Z, Z};
  v2 yr[4] = {Z, Z, Z, Z};
  v2 sw0 = Z, sw1 = Z, yeq = Z;
  float yeq96 = 0.f, ytc = 0.f;
  v2 uc = Z, ud = Z, msc = Z, msd = Z;

  float sigv = 0.f, tauv = 0.f;
  float sa = 0.f;                 // sigma*act (per-lane scalar, broadcast)
  v2 sr = Z, ssw = Z, smd[3] = {Z, Z, Z};

  // ---------------- phase B: row dots / dual updates ----------------
  auto phaseB = [&](bool power) {
    // wave-uniform serial chains FIRST so they overlap the dual updates
    // (they read only xbar, which phaseB never writes).
    {
      float s95 = __int_as_float(__builtin_amdgcn_readlane(__float_as_int(xbs.y), 47));
      if (power) yeq96 = s95; else yeq96 += sigv * s95;
      float tot = wave_sum64(xbc.x + xbc.y);
      if (power) ytc = 0.25f * tot;
      else ytc = fmaxf(ytc + sigv * (0.25f * tot - 1200.f), 0.f);
    }
    // xbar neighbor shifts. prev(t-1): .x needs lane-1's odd; .y same-lane even.
    v2 pxc  = { dpp_shr1(xbc.y),  xbc.x };
    v2 pxd  = { dpp_shr1(xbd.y),  xbd.x };
    v2 pxs  = { dpp_shr1(xbs.y),  xbs.x };
    v2 pxyc = { dpp_shr1(xbyc.y), xbyc.x };
    v2 pxyd = { dpp_shr1(xbyd.y), xbyd.x };
    // next(t+k): chained shl1 (lanes >=48 are exact zeros -> edge fills 0).
    float a1 = dpp_shl1(xbyc.x), b1 = dpp_shl1(xbyc.y), c1 = dpp_shl1(a1);
    v2 nyc1 = { xbyc.y, a1 };
    v2 nyc2 = { a1, b1 };
    v2 nyc3 = { b1, c1 };
    float a2 = dpp_shl1(xbyd.x), b2 = dpp_shl1(xbyd.y), c2 = dpp_shl1(a2);
    v2 nyd1 = { xbyd.y, a2 };
    v2 nyd2 = { a2, b2 };
    v2 nyd3 = { b2, c2 };

    const v2 c_ = xbc, d_ = xbd, yc_ = xbyc, yd_ = xbyd, s_ = xbs;
    // BOX (13 rows; in power mode xbar is act-masked so raw dots are 0 on l>=48)
    if (power) {
      yb[0] = c_;   yb[1] = d_;
      yb[2] = -c_;  yb[3] = -d_;
      yb[4] = -yc_; yb[5] = yc_;
      yb[6] = -yd_; yb[7] = yd_;
      yb[8] = -s_;  yb[9] = s_;
      yb[10] = yc_ + yd_;
      yb[11] = c_ - 195.f * yc_;
      yb[12] = d_ - 195.f * yd_;
    } else {
      yb[0]  = __builtin_elementwise_max(yb[0]  + sa * (c_ - 195.f), Z);
      yb[1]  = __builtin_elementwise_max(yb[1]  + sa * (d_ - 195.f), Z);
      yb[2]  = __builtin_elementwise_max(yb[2]  - sa * c_,           Z);
      yb[3]  = __builtin_elementwise_max(yb[3]  - sa * d_,           Z);
      yb[4]  = __builtin_elementwise_max(yb[4]  - sa * yc_,          Z);
      yb[5]  = __builtin_elementwise_max(yb[5]  + sa * (yc_ - 1.f),  Z);
      yb[6]  = __builtin_elementwise_max(yb[6]  - sa * yd_,          Z);
      yb[7]  = __builtin_elementwise_max(yb[7]  + sa * (yd_ - 1.f),  Z);
      yb[8]  = __builtin_elementwise_max(yb[8]  - sa * s_,           Z);
      yb[9]  = __builtin_elementwise_max(yb[9]  + sa * (s_ - 800.f), Z);
      yb[10] = __builtin_elementwise_max(yb[10] + sa * (yc_ + yd_ - 1.f), Z);
      yb[11] = __builtin_elementwise_max(yb[11] + sa * (c_ - 195.f * yc_), Z);
      yb[12] = __builtin_elementwise_max(yb[12] + sa * (d_ - 195.f * yd_), Z);
    }
    // MIN-DURATION: dot(k,t) = v[t] - v[t-1] - v[t+k]
    {
      v2 base_c = yc_ - pxyc, base_d = yd_ - pxyd;
      v2 dc1 = base_c - nyc1, dc2 = base_c - nyc2, dc3 = base_c - nyc3;
      v2 dd1 = base_d - nyd1, dd2 = base_d - nyd2, dd3 = base_d - nyd3;
      if (power) {
        ymc[0] = m_md[0] * dc1; ymc[1] = m_md[1] * dc2; ymc[2] = m_md[2] * dc3;
        ymd[0] = m_md[0] * dd1; ymd[1] = m_md[1] * dd2; ymd[2] = m_md[2] * dd3;
      } else {
        ymc[0] = __builtin_elementwise_max(ymc[0] + smd[0] * dc1, Z);
        ymc[1] = __builtin_elementwise_max(ymc[1] + smd[1] * dc2, Z);
        ymc[2] = __builtin_elementwise_max(ymc[2] + smd[2] * dc3, Z);
        ymd[0] = __builtin_elementwise_max(ymd[0] + smd[0] * dd1, Z);
        ymd[1] = __builtin_elementwise_max(ymd[1] + smd[1] * dd2, Z);
        ymd[2] = __builtin_elementwise_max(ymd[2] + smd[2] * dd3, Z);
      }
    }
    // RAMP
    {
      v2 dc = c_ - pxc, dd = d_ - pxd;
      if (power) {
        yr[0] = m_r * dc; yr[1] = -m_r * dc;
        yr[2] = m_r * dd; yr[3] = -m_r * dd;
      } else {
        yr[0] = __builtin_elementwise_max(yr[0] + sr * (dc - 65.f),  Z);
        yr[1] = __builtin_elementwise_max(yr[1] + sr * (-dc - 65.f), Z);
        yr[2] = __builtin_elementwise_max(yr[2] + sr * (dd - 65.f),  Z);
        yr[3] = __builtin_elementwise_max(yr[3] + sr * (-dd - 65.f), Z);
      }
    }
    // SWITCH
    {
      v2 d0 = yc_ + nyd1, d1 = yd_ + nyc1;
      if (power) { sw0 = m_sw * d0; sw1 = m_sw * d1; }
      else {
        sw0 = __builtin_elementwise_max(sw0 + ssw * (d0 - 1.f), Z);
        sw1 = __builtin_elementwise_max(sw1 + ssw * (d1 - 1.f), Z);
      }
    }
    // EQUALITY (free dual)
    {
      v2 de = s_ - pxs + cET * c_ + cDE * d_;
      if (power) yeq = act * de;
      else yeq += sa * de;
    }
    // combos consumed by next gather (masked-zero rows keep these exact)
    uc = yr[0] - yr[1];
    ud = yr[2] - yr[3];
    msc = ymc[0] + ymc[1] + ymc[2];
    msd = ymd[0] + ymd[1] + ymd[2];
  };

  // ---------------- phase A: K^T y gather, all 10 column-chunks ----------------
  v2 gc, gd, gyc, gyd, gs;
  auto gather = [&]() {
    v2 ucn  = { uc.y,  dpp_shl1(uc.x) };
    v2 udn  = { ud.y,  dpp_shl1(ud.x) };
    v2 mscn = { msc.y, dpp_shl1(msc.x) };
    v2 msdn = { msd.y, dpp_shl1(msd.x) };
    float tdn = dpp_shl1(yeq.x);
    v2 eqn = { yeq.y, (lane == 47) ? -yeq96 : tdn };
    v2 sw1p = { dpp_shr1(sw1.y), sw1.x };
    v2 sw0p = { dpp_shr1(sw0.y), sw0.x };
    v2 pc1 = { dpp_shr1(ymc[0].y), ymc[0].x };
    v2 pc2 = { dpp_shr1(ymc[1].x), dpp_shr1(ymc[1].y) };
    v2 pc3 = { dpp_shr1(dpp_shr1(ymc[2].y)), dpp_shr1(ymc[2].x) };
    v2 pd1 = { dpp_shr1(ymd[0].y), ymd[0].x };
    v2 pd2 = { dpp_shr1(ymd[1].x), dpp_shr1(ymd[1].y) };
    v2 pd3 = { dpp_shr1(dpp_shr1(ymd[2].y)), dpp_shr1(ymd[2].x) };
    gc = (yb[0] - yb[2] + yb[11]) + uc - ucn + 0.25f * ytc + cET * yeq;
    gd = (yb[1] - yb[3] + yb[12]) + ud - udn + cDE * yeq;
    gyc = (-yb[4] + yb[5] + yb[10] - 195.f * yb[11])
        + sw0 + sw1p + msc - mscn - pc1 - pc2 - pc3;
    gyd = (-yb[6] + yb[7] + yb[10] - 195.f * yb[12])
        + sw1 + sw0p + msd - msdn - pd1 - pd2 - pd3;
    gs = (-yb[8] + yb[9]) + yeq - eqn;
  };

  // ================= power iteration: ||K||_2 =================
  xbc = act; xbd = act; xbyc = act; xbyd = act; xbs = act;
  float lam2 = 1.f;
  for (int pit = 0; pit < PITER; ++pit) {
    phaseB(true);
    gather();
    v2 pv = gc * gc + gd * gd + gyc * gyc + gyd * gyd + gs * gs;
    float part = (pv.x + pv.y) * act;
    lam2 = sqrtf(wave_sum64(part));
    float inv = act / lam2;
    xbc = gc * inv; xbd = gd * inv;
    xbyc = gyc * inv; xbyd = gyd * inv; xbs = gs * inv;
  }
  tauv = (float)(0.9 / sqrt((double)lam2));
  sigv = tauv;
  // sigma*mask row multipliers (loop-invariant)
  sa = sigv * act;
  sr = sigv * m_r;
  ssw = sigv * m_sw;
#pragma unroll
  for (int k = 0; k < 3; ++k) smd[k] = sigv * m_md[k];

  // reset all state for PDHG
#pragma unroll
  for (int i = 0; i < 13; ++i) yb[i] = Z;
#pragma unroll
  for (int k = 0; k < 3; ++k) { ymc[k] = Z; ymd[k] = Z; }
#pragma unroll
  for (int k = 0; k < 4; ++k) yr[k] = Z;
  sw0 = Z; sw1 = Z; yeq = Z;
  uc = Z; ud = Z; msc = Z; msd = Z;
  xbc = Z; xbd = Z; xbyc = Z; xbyd = Z; xbs = Z;
  xc = Z; xd = Z; xyc = Z; xyd = Z; xs = Z;
  yeq96 = 0.f; ytc = 0.f;

  // q loads (lanes >=48 nullified by tau*act)
  {
    const int l2 = (lane < 48) ? lane : 0;
    float p0 = price[bi * 96 + 2 * l2];
    float p1 = price[bi * 96 + 2 * l2 + 1];
    qc = (v2){ 0.25f * p0, 0.25f * p1 };
    qd = (v2){ -0.25f * p0, -0.25f * p1 };
  }

  // ================= PDHG =================
  const float ta = tauv * act;
#pragma unroll 2
  for (int it = 0; it < NITER; ++it) {
    gather();
    {
      v2 xa;
      xa = xc  - ta * (qc + gc);  xbc  = 2.f * xa - xc;  xc  = xa;
      xa = xd  - ta * (qd + gd);  xbd  = 2.f * xa - xd;  xd  = xa;
      xa = xyc - ta * gyc;        xbyc = 2.f * xa - xyc; xyc = xa;
      xa = xyd - ta * gyd;        xbyd = 2.f * xa - xyd; xyd = xa;
      xa = xs  - ta * gs;         xbs  = 2.f * xa - xs;  xs  = xa;
    }
    phaseB(false);
  }

  // output: c then d, each (256,96)
  if (lane < 48) {
    out[bi * 96 + 2 * lane]             = xc.x;
    out[bi * 96 + 2 * lane + 1]         = xc.y;
    out[24576 + bi * 96 + 2 * lane]     = xd.x;
    out[24576 + bi * 96 + 2 * lane + 1] = xd.y;
  }
}

extern "C" void kernel_launch(void* const* d_in, const int* in_sizes, int n_in,
                              void* d_out, int out_size, void* d_ws, size_t ws_size,
                              hipStream_t stream) {
  const float* price = (const float*)d_in[0];
  float* outp = (float*)d_out;
  hipLaunchKernelGGL(lp_solve_kernel, dim3(256), dim3(64), 0, stream, price, outp);
}